// Round 1
// baseline (328.335 us; speedup 1.0000x reference)
//
#include <hip/hip_runtime.h>

#define DEVFN __device__ __forceinline__

typedef __bf16 bf16x8 __attribute__((ext_vector_type(8)));
typedef float f32x4 __attribute__((ext_vector_type(4)));
typedef float float4_t __attribute__((ext_vector_type(4)));
typedef unsigned short ushort8_t __attribute__((ext_vector_type(8)));
typedef unsigned short ushort4_t __attribute__((ext_vector_type(4)));

constexpr int Bd = 8, Cd = 512, Nd = 4096, Dd = 64;

DEVFN unsigned short f2bf(float f) {
    union { float f; unsigned int u; } v; v.f = f;
    unsigned int r = (v.u + 0x7FFFu + ((v.u >> 16) & 1u)) >> 16;
    return (unsigned short)r;
}

DEVFN bf16x8 ld_bf8(const unsigned short* p) {
    ushort8_t u = *(const ushort8_t*)p;
    return __builtin_bit_cast(bf16x8, u);
}

DEVFN f32x4 mfma16(bf16x8 a, bf16x8 b, f32x4 c) {
    return __builtin_amdgcn_mfma_f32_16x16x32_bf16(a, b, c, 0, 0, 0);
}

// ---------------- K0: convert weights to bf16 ----------------
__global__ __launch_bounds__(256) void k_cvtw(
    const float* __restrict__ Wq, const float* __restrict__ Wk,
    const float* __restrict__ Wv, const float* __restrict__ Wo,
    unsigned short* __restrict__ w4)
{
    int i = blockIdx.x * 256 + threadIdx.x;   // 0..32767
    w4[i]          = f2bf(Wq[i]);
    w4[32768 + i]  = f2bf(Wk[i]);
    w4[65536 + i]  = f2bf(Wv[i]);
    w4[98304 + i]  = f2bf(Wo[i]);
}

// ---------------- K1: QKV projections ----------------
// q_nd[b][n][d], k_nd[b][n][d] (N,D);  v_dn[b][d][n] (D,N)
__global__ __launch_bounds__(256) void k_qkv(
    const float* __restrict__ x,
    const unsigned short* __restrict__ wq,
    const unsigned short* __restrict__ wk,
    const unsigned short* __restrict__ wv,
    const float* __restrict__ bq, const float* __restrict__ bk, const float* __restrict__ bv,
    unsigned short* __restrict__ q_nd, unsigned short* __restrict__ k_nd,
    unsigned short* __restrict__ v_dn)
{
    const int b   = blockIdx.y;
    const int n0  = blockIdx.x * 64;
    const int tid = threadIdx.x, wid = tid >> 6, l = tid & 63;
    const int lo  = l & 15, hi = l >> 4;
    const int n0w = n0 + wid * 16;
    const float* xb = x + (size_t)b * Cd * Nd;

    __shared__ unsigned short t_lds[4][16][72];
    __shared__ unsigned short vt_s[64][72];

    f32x4 accq[4] = {}, acck[4] = {}, accv[4] = {};

    for (int c0 = 0; c0 < Cd; c0 += 32) {
        // B-fragment: B[k=c][col=n] = x[c][n]
        ushort8_t ux;
        #pragma unroll
        for (int j = 0; j < 8; ++j)
            ux[j] = f2bf(xb[(size_t)(c0 + hi * 8 + j) * Nd + n0w + lo]);
        bf16x8 bx = __builtin_bit_cast(bf16x8, ux);
        #pragma unroll
        for (int ds = 0; ds < 4; ++ds) {
            const int wrow = (ds * 16 + lo) * Cd + c0 + hi * 8;
            accq[ds] = mfma16(ld_bf8(wq + wrow), bx, accq[ds]);
            acck[ds] = mfma16(ld_bf8(wk + wrow), bx, acck[ds]);
            accv[ds] = mfma16(ld_bf8(wv + wrow), bx, accv[ds]);
        }
    }

    const int row = l >> 2, dg = l & 3;

    // ---- q: D[row=d][col=n] -> LDS transpose -> (N,D) coalesced ----
    #pragma unroll
    for (int ds = 0; ds < 4; ++ds) {
        ushort4_t u4;
        #pragma unroll
        for (int r = 0; r < 4; ++r) u4[r] = f2bf(accq[ds][r] + bq[ds*16 + hi*4 + r]);
        *(ushort4_t*)&t_lds[wid][lo][ds*16 + hi*4] = u4;
    }
    __syncthreads();
    {
        ushort8_t a0 = *(const ushort8_t*)&t_lds[wid][row][dg*16];
        ushort8_t a1 = *(const ushort8_t*)&t_lds[wid][row][dg*16 + 8];
        unsigned short* dst = q_nd + ((size_t)b * Nd + n0 + wid*16 + row) * 64 + dg*16;
        *(ushort8_t*)dst = a0; *(ushort8_t*)(dst + 8) = a1;
    }
    __syncthreads();

    // ---- k ----
    #pragma unroll
    for (int ds = 0; ds < 4; ++ds) {
        ushort4_t u4;
        #pragma unroll
        for (int r = 0; r < 4; ++r) u4[r] = f2bf(acck[ds][r] + bk[ds*16 + hi*4 + r]);
        *(ushort4_t*)&t_lds[wid][lo][ds*16 + hi*4] = u4;
    }
    __syncthreads();
    {
        ushort8_t a0 = *(const ushort8_t*)&t_lds[wid][row][dg*16];
        ushort8_t a1 = *(const ushort8_t*)&t_lds[wid][row][dg*16 + 8];
        unsigned short* dst = k_nd + ((size_t)b * Nd + n0 + wid*16 + row) * 64 + dg*16;
        *(ushort8_t*)dst = a0; *(ushort8_t*)(dst + 8) = a1;
    }
    __syncthreads();

    // ---- v: block-wide (64 d x 64 n) tile -> (D,N) coalesced ----
    #pragma unroll
    for (int ds = 0; ds < 4; ++ds) {
        #pragma unroll
        for (int r = 0; r < 4; ++r)
            vt_s[ds*16 + hi*4 + r][wid*16 + lo] = f2bf(accv[ds][r] + bv[ds*16 + hi*4 + r]);
    }
    __syncthreads();
    {
        const int d = tid >> 2, ng = tid & 3;
        ushort8_t a0 = *(const ushort8_t*)&vt_s[d][ng*16];
        ushort8_t a1 = *(const ushort8_t*)&vt_s[d][ng*16 + 8];
        unsigned short* dst = v_dn + ((size_t)b * Dd + d) * Nd + n0 + ng*16;
        *(ushort8_t*)dst = a0; *(ushort8_t*)(dst + 8) = a1;
    }
}

// ---------------- K2: flash attention ----------------
__global__ __launch_bounds__(256) void k_attn(
    const unsigned short* __restrict__ q_nd,
    const unsigned short* __restrict__ k_nd,
    const unsigned short* __restrict__ v_dn,
    unsigned short* __restrict__ o_nd)
{
    const int bid = blockIdx.x;
    const int b   = bid & 7;            // round-robin XCD dispatch -> batch-per-XCD L2 locality
    const int n0  = (bid >> 3) * 64;
    const int tid = threadIdx.x, wid = tid >> 6, l = tid & 63;
    const int lo  = l & 15, hi = l >> 4;
    const int n0w = n0 + wid * 16;

    __shared__ unsigned short p_lds[4][16][72];

    const unsigned short* qb = q_nd + (size_t)b * Nd * Dd;
    const unsigned short* kb = k_nd + (size_t)b * Nd * Dd;
    const unsigned short* vb = v_dn + (size_t)b * Dd * Nd;

    bf16x8 aq[2];
    #pragma unroll
    for (int kc = 0; kc < 2; ++kc)
        aq[kc] = ld_bf8(qb + (size_t)(n0w + lo) * 64 + kc*32 + hi*8);

    f32x4 acc[4] = {};
    float m_st[4], l_st[4];
    #pragma unroll
    for (int r = 0; r < 4; ++r) { m_st[r] = -1e30f; l_st[r] = 0.f; }

    for (int m0 = 0; m0 < Nd; m0 += 64) {
        // S = Q K^T   (16n x 64m)
        f32x4 s[4] = {};
        #pragma unroll
        for (int ms = 0; ms < 4; ++ms) {
            #pragma unroll
            for (int kc = 0; kc < 2; ++kc) {
                bf16x8 bk8 = ld_bf8(kb + (size_t)(m0 + ms*16 + lo) * 64 + kc*32 + hi*8);
                s[ms] = mfma16(aq[kc], bk8, s[ms]);
            }
        }
        // online softmax; row n = n0w + hi*4 + r, cols spread over (ms, lo)
        float rm[4], sc[4];
        #pragma unroll
        for (int r = 0; r < 4; ++r) {
            float mx = fmaxf(fmaxf(s[0][r], s[1][r]), fmaxf(s[2][r], s[3][r]));
            #pragma unroll
            for (int off = 1; off < 16; off <<= 1)
                mx = fmaxf(mx, __shfl_xor(mx, off, 64));
            float mn = fmaxf(m_st[r], mx);
            sc[r] = __expf(m_st[r] - mn);
            m_st[r] = mn;
            rm[r] = mn;
        }
        float p[4][4];
        #pragma unroll
        for (int ms = 0; ms < 4; ++ms) {
            #pragma unroll
            for (int r = 0; r < 4; ++r)
                p[ms][r] = __expf(s[ms][r] - rm[r]);
        }
        #pragma unroll
        for (int r = 0; r < 4; ++r) {
            float ps = (p[0][r] + p[1][r]) + (p[2][r] + p[3][r]);
            #pragma unroll
            for (int off = 1; off < 16; off <<= 1)
                ps += __shfl_xor(ps, off, 64);
            l_st[r] = l_st[r] * sc[r] + ps;
        }
        #pragma unroll
        for (int ds = 0; ds < 4; ++ds) {
            #pragma unroll
            for (int r = 0; r < 4; ++r)
                acc[ds][r] *= sc[r];
        }
        // P -> wave-private LDS (in-order LDS within wave; no barrier needed)
        #pragma unroll
        for (int ms = 0; ms < 4; ++ms) {
            #pragma unroll
            for (int r = 0; r < 4; ++r)
                p_lds[wid][hi*4 + r][ms*16 + lo] = f2bf(p[ms][r]);
        }
        // PV: A = P (16n x 64m), B = v_dn (m x d, contiguous along m)
        bf16x8 ap[2];
        #pragma unroll
        for (int kc = 0; kc < 2; ++kc)
            ap[kc] = ld_bf8(&p_lds[wid][lo][kc*32 + hi*8]);
        #pragma unroll
        for (int ds = 0; ds < 4; ++ds) {
            #pragma unroll
            for (int kc = 0; kc < 2; ++kc) {
                bf16x8 bv8 = ld_bf8(vb + (size_t)(ds*16 + lo) * Nd + m0 + kc*32 + hi*8);
                acc[ds] = mfma16(ap[kc], bv8, acc[ds]);
            }
        }
    }
    // epilogue: normalize, store o (N,D) bf16
    #pragma unroll
    for (int ds = 0; ds < 4; ++ds) {
        #pragma unroll
        for (int r = 0; r < 4; ++r) {
            float o = acc[ds][r] / l_st[r];
            o_nd[((size_t)b * Nd + n0w + hi*4 + r) * 64 + ds*16 + lo] = f2bf(o);
        }
    }
}

// ---------------- K3: output projection + residual ----------------
__global__ __launch_bounds__(256) void k_oproj(
    const unsigned short* __restrict__ o_nd,
    const unsigned short* __restrict__ wo,
    const float* __restrict__ bo,
    const float* __restrict__ gamma,
    const float* __restrict__ x,
    float* __restrict__ out)
{
    const int b   = blockIdx.y;
    const int n0  = blockIdx.x * 64;
    const int tid = threadIdx.x, wid = tid >> 6, l = tid & 63;
    const int lo  = l & 15, hi = l >> 4;
    const int n0w = n0 + wid * 16;
    const float g = gamma[0];

    bf16x8 ao[2];
    #pragma unroll
    for (int kc = 0; kc < 2; ++kc)
        ao[kc] = ld_bf8(o_nd + ((size_t)b * Nd + n0w + lo) * 64 + kc*32 + hi*8);

    for (int ct = 0; ct < 32; ++ct) {
        f32x4 acc = {};
        #pragma unroll
        for (int kc = 0; kc < 2; ++kc) {
            bf16x8 bw = ld_bf8(wo + (ct*16 + lo) * 64 + kc*32 + hi*8);
            acc = mfma16(ao[kc], bw, acc);
        }
        const int c = ct*16 + lo;
        const float bc = bo[c];
        const size_t base = ((size_t)b * Cd + c) * Nd + n0w + hi*4;
        float4_t xv = *(const float4_t*)(x + base);
        float4_t ov;
        #pragma unroll
        for (int r = 0; r < 4; ++r) ov[r] = g * (acc[r] + bc) + xv[r];
        *(float4_t*)(out + base) = ov;
    }
}

extern "C" void kernel_launch(void* const* d_in, const int* in_sizes, int n_in,
                              void* d_out, int out_size, void* d_ws, size_t ws_size,
                              hipStream_t stream) {
    (void)in_sizes; (void)n_in; (void)out_size; (void)ws_size;
    const float* x  = (const float*)d_in[0];
    const float* Wq = (const float*)d_in[1];
    const float* bq = (const float*)d_in[2];
    const float* Wk = (const float*)d_in[3];
    const float* bk = (const float*)d_in[4];
    const float* Wv = (const float*)d_in[5];
    const float* bv = (const float*)d_in[6];
    const float* Wo = (const float*)d_in[7];
    const float* bo = (const float*)d_in[8];
    const float* gm = (const float*)d_in[9];
    float* out = (float*)d_out;

    unsigned short* w4   = (unsigned short*)d_ws;          // 4 x 32768 bf16 weights
    unsigned short* q_nd = w4 + 131072;
    unsigned short* k_nd = q_nd + (size_t)Bd * Nd * Dd;
    unsigned short* v_dn = k_nd + (size_t)Bd * Nd * Dd;
    unsigned short* o_nd = v_dn + (size_t)Bd * Nd * Dd;

    k_cvtw<<<128, 256, 0, stream>>>(Wq, Wk, Wv, Wo, w4);
    dim3 g1(Nd / 64, Bd);
    k_qkv<<<g1, 256, 0, stream>>>(x, w4, w4 + 32768, w4 + 65536, bq, bk, bv, q_nd, k_nd, v_dn);
    k_attn<<<512, 256, 0, stream>>>(q_nd, k_nd, v_dn, o_nd);
    k_oproj<<<g1, 256, 0, stream>>>(o_nd, w4 + 98304, bo, gm, x, out);
}